// Round 6
// baseline (932.518 us; speedup 1.0000x reference)
//
#include <hip/hip_runtime.h>

// 2-layer LSTM, B=2048, T=4096, IN=1, H=8, OUT=1, fp32.
//
// R13 = R12 with instruction-count cuts (R11/R12 showed: DS latency is
// covered; wall tracks VALU inst count ~10cy/pair/inst):
//  1. Paired-k packed-FP32 dots: hA={h[j],h[j^1]}, hB={h[j^2],h[j^3]}
//     (DPP gather writes pair elements directly); each dot =
//     pk_mul/pk_fma + horizontal add. pk asm forms proven in R9.
//  2. Bias folded into pk init c-operand: tP={wx*xt+bias, 0}, b2P={b2,0}.
//  3. c-scale fold: track c' = c*(-2log2e); g~ activation pre-scaled
//     (sA'=2*N2L2E, oA'=-N2L2E) so e=exp2(c') needs no mul.
//
// Layout: 1 seq/wave64, lane = L*32 + j*4 + g (g=gate i,f,g~,o; j=unit;
// L=layer). 2048 waves = 2 waves/SIMD.
// Far-half dot: each lane computes the far partial OF ITS MIRROR LANE's
// row (weights W[row(lane^16)][j^i]) from its near h; s1 ships via
// permlane16_swap (VALU, R11-verified), s2 via ds_swizzle xor16 (slack-
// covered). Cross-layer: d2 ships via ds_bpermute lane^32, consumed TWO
// iterations later: recvB(m) = d2(m-2) = Wih1 . h1(m-3)  =>  L1 runs
// THREE iters behind L0. Projection at iter m uses h2(m-4) -> store
// op[m-4]; fills = iters 0,1,2; steady m = 4..Tsz+3.
// Gates pre-scaled by -log2e (g~ rows -2log2e): act = rcp(1+exp2(z)).

constexpr int Bsz = 2048;
constexpr int Tsz = 4096;

typedef int   v2i __attribute__((ext_vector_type(2)));
typedef float v2f __attribute__((ext_vector_type(2)));

template <int CTRL>
__device__ __forceinline__ float dpp(float v) {
    return __int_as_float(
        __builtin_amdgcn_mov_dpp(__float_as_int(v), CTRL, 0xF, 0xF, true));
}
// quad_perm bcast0..3 = 0x00,0x55,0xAA,0xFF; quad xor3 = 0x1B;
// row_half_mirror (xor7) = 0x141; row_mirror (xor15) = 0x140

// v[lane^16] via V_PERMLANE16_SWAP_B32 (VALU; verified bit-exact in R11).
__device__ __forceinline__ float xchg16(float v, bool hi16) {
    const int vi = __float_as_int(v);
    v2i p = __builtin_amdgcn_permlane16_swap(vi, vi, false, false);
    return __int_as_float(hi16 ? p.x : p.y);
}

__device__ __forceinline__ float swz16(float v) {
    // ds_swizzle bit mode, xor 0x10 within each 32-lane group
    return __int_as_float(
        __builtin_amdgcn_ds_swizzle(__float_as_int(v), (16 << 10) | 0x1f));
}

__device__ __forceinline__ float bperm(int addr, float v) {
    return __int_as_float(__builtin_amdgcn_ds_bpermute(addr, __float_as_int(v)));
}

// gfx90a+/gfx950 packed fp32 (R9-proven asm forms).
__device__ __forceinline__ v2f pk_fma(v2f a, v2f b, v2f c) {
    v2f d;
    asm("v_pk_fma_f32 %0, %1, %2, %3" : "=v"(d) : "v"(a), "v"(b), "v"(c));
    return d;
}
__device__ __forceinline__ v2f pk_mul(v2f a, v2f b) {
    v2f d;
    asm("v_pk_mul_f32 %0, %1, %2" : "=v"(d) : "v"(a), "v"(b));
    return d;
}

__global__ void __launch_bounds__(256, 2) lstm2_pk1(
    const float* __restrict__ x,      // [B, T]
    const float* __restrict__ Wih0,   // [32, 1]
    const float* __restrict__ Whh0,   // [32, 8]
    const float* __restrict__ bih0,   // [32]
    const float* __restrict__ bhh0,   // [32]
    const float* __restrict__ Wih1,   // [32, 8]
    const float* __restrict__ Whh1,   // [32, 8]
    const float* __restrict__ bih1,   // [32]
    const float* __restrict__ bhh1,   // [32]
    const float* __restrict__ Wlin,   // [1, 8]
    const float* __restrict__ blin,   // [1]
    float* __restrict__ out)          // [B, T]
{
    const int tid  = threadIdx.x;
    const int lane = tid & 63;
    const int g    = lane & 3;
    const int j    = (lane >> 2) & 7;
    const int L    = (lane >> 5) & 1;
    const int seq  = blockIdx.x * 4 + (tid >> 6);

    const int jm = j ^ 4;             // mirror lane's unit
    const int r  = g * 8 + j;         // own gate row
    const int rm = g * 8 + jm;        // mirror lane's gate row

    const bool hi16 = (lane & 16) != 0;

    const float NL2E  = -1.4426950408889634f;
    const float N2L2E = -2.8853900817779268f;
    const bool  isG   = (g == 2);
    const float ws    = isG ? N2L2E : NL2E;
    // c-scale fold: g~ lanes produce tanh(g)*N2L2E directly
    const float sA    = isG ? 2.0f * N2L2E : 1.0f;
    const float oA    = isG ? -N2L2E : 0.0f;

    const float* __restrict__ Whh = L ? Whh1 : Whh0;
    const float* __restrict__ bih = L ? bih1 : bih0;
    const float* __restrict__ bhh = L ? bhh1 : bhh0;

    // weight pairs over k = j^i: A covers i=0,1; B covers i=2,3
    float wn1[4], wm1[4], wn2[4], wm2[4];
#pragma unroll
    for (int i = 0; i < 4; ++i) {
        const int k = j ^ i;
        wn1[i] = Whh[r * 8 + k] * ws;
        wm1[i] = Whh[rm * 8 + k] * ws;
        wn2[i] = L ? Wlin[k] : Wih1[r * 8 + k] * ws;
        wm2[i] = L ? Wlin[k] : Wih1[rm * 8 + k] * ws;
    }
    const v2f wAn1 = {wn1[0], wn1[1]}, wBn1 = {wn1[2], wn1[3]};
    const v2f wAm1 = {wm1[0], wm1[1]}, wBm1 = {wm1[2], wm1[3]};
    const v2f wAn2 = {wn2[0], wn2[1]}, wBn2 = {wn2[2], wn2[3]};
    const v2f wAm2 = {wm2[0], wm2[1]}, wBm2 = {wm2[2], wm2[3]};

    const float bias = (bih[r] + bhh[r]) * ws;
    const float wx   = L ? 0.0f : Wih0[r] * ws;
    const float b2   = L ? blin[0] : 0.0f;
    const float mL   = L ? 1.0f : 0.0f;
    const float keep = 1.0f - mL;
    const int  xaddr = (lane ^ 32) * 4;   // bpermute: cross layer halves

    const v2f b2P = {b2, 0.0f};
    v2f tP; tP.x = 0.0f; tP.y = 0.0f;     // .x rewritten per body, .y stays 0

    const float* __restrict__ xp = x + (size_t)seq * Tsz;
    float* __restrict__ op       = out + (size_t)seq * Tsz;
    const bool storeLane = (lane == 32);

    v2f hA = {0.0f, 0.0f};   // {h[j],   h[j^1]}
    v2f hB = {0.0f, 0.0f};   // {h[j^2], h[j^3]}
    float cs = 0.0f;         // c' = c * N2L2E (scale-folded cell state)
    float recvA = 0.0f, recvB = 0.0f;

    auto body = [&](float xt, bool fill, float* storePtr) {
        // -- mirror dots from entering h-pairs (= h(m-1)); ship early
        v2f accm1 = pk_mul(wAm1, hA);
        accm1 = pk_fma(wBm1, hB, accm1);
        const float am1 = accm1.x + accm1.y;
        v2f accm2 = pk_mul(wAm2, hA);
        accm2 = pk_fma(wBm2, hB, accm2);
        const float am2 = accm2.x + accm2.y;
        const float s2 = swz16(am2);          // off-chain: DS, consumed at tail
        const float s1 = xchg16(am1, hi16);   // on-chain: VALU permlane swap

        // -- near dots (bias folded into pk init)
        tP.x = fmaf(wx, xt, bias);
        v2f accn1 = pk_fma(wAn1, hA, tP);
        accn1 = pk_fma(wBn1, hB, accn1);
        const float an1 = accn1.x + accn1.y;
        v2f accn2 = pk_fma(wAn2, hA, b2P);
        accn2 = pk_fma(wBn2, hB, accn2);
        const float an2 = accn2.x + accn2.y;

        // -- z: near + far(ship) + cross-layer dot from 2 iters ago
        const float z = fmaf(mL, recvB, an1 + s1);

        // -- activation (pre-scaled): sig, or tanh*N2L2E for g~ lanes
        float a = fmaf(sA,
                       __builtin_amdgcn_rcpf(1.0f + __builtin_amdgcn_exp2f(z)),
                       oA);
        const float gi = dpp<0x00>(a);
        const float gf = dpp<0x55>(a);
        const float gG = dpp<0xAA>(a);        // = tanh(g)*N2L2E (pre-scaled)
        const float go = dpp<0xFF>(a);
        cs = fmaf(gf, cs, gi * gG);           // c' = c*N2L2E
        const float e  = __builtin_amdgcn_exp2f(cs);   // no mul needed
        const float th = fmaf(2.0f, __builtin_amdgcn_rcpf(1.0f + e), -1.0f);
        float h = go * th;

        if (fill) { h *= keep; cs *= keep; }  // keep L1 state at zero

        // -- near-h gather for next iter, written into the pk pairs
        const float m7  = dpp<0x141>(h);      // ^7
        const float m15 = dpp<0x140>(h);      // ^15
        hA.x = h;                             // j
        hA.y = dpp<0x1B>(m7);                 // ^7^3  = ^4  -> j^1
        hB.x = dpp<0x141>(m15);               // ^15^7 = ^8  -> j^2
        hB.y = dpp<0x1B>(m15);                // ^15^3 = ^12 -> j^3

        // -- tail: full spare dot (uses h(m-1) values), store, ship
        const float d2 = an2 + s2;            // L0: Wih1.h1(m-1); L1: proj(h2(m-4))
        if (storePtr && storeLane) *storePtr = d2;
        recvB = recvA;                        // recvB for iter m+1 = d2(m-1)
        recvA = bperm(xaddr, d2);             // d2(m), off-chain (2-iter slack)
    };

    // ---- fills: iters 0,1,2 keep L1 state zero; iter 3 = L1 step 0
    body(xp[0], true, nullptr);
    body(xp[1], true, nullptr);
    body(xp[2], true, nullptr);
    body(xp[3], false, nullptr);             // computes h2(0); proj invalid

    // ---- steady, unrolled x4: m = 4 .. Tsz+3, store op[m-4]
    float xc[4];
#pragma unroll
    for (int u = 0; u < 4; ++u) xc[u] = xp[4 + u];   // x(4..7), Tsz >> 8
    for (int ck = 0; ck < Tsz / 4; ++ck) {
        const int base = 4 + 4 * ck;
        float xf[4];
#pragma unroll
        for (int u = 0; u < 4; ++u) {
            int idx = base + 4 + u;
            idx = (idx < Tsz) ? idx : (Tsz - 1);
            xf[u] = xp[idx];                 // prefetch next chunk
        }
#pragma unroll
        for (int u = 0; u < 4; ++u)
            body(xc[u], false, op + (4 * ck + u));   // op[m-4]
#pragma unroll
        for (int u = 0; u < 4; ++u) xc[u] = xf[u];
    }
}

extern "C" void kernel_launch(void* const* d_in, const int* in_sizes, int n_in,
                              void* d_out, int out_size, void* d_ws, size_t ws_size,
                              hipStream_t stream) {
    const float* x    = (const float*)d_in[0];
    const float* Wih0 = (const float*)d_in[1];
    const float* Whh0 = (const float*)d_in[2];
    const float* bih0 = (const float*)d_in[3];
    const float* bhh0 = (const float*)d_in[4];
    const float* Wih1 = (const float*)d_in[5];
    const float* Whh1 = (const float*)d_in[6];
    const float* bih1 = (const float*)d_in[7];
    const float* bhh1 = (const float*)d_in[8];
    const float* Wlin = (const float*)d_in[9];
    const float* blin = (const float*)d_in[10];
    float* out = (float*)d_out;

    dim3 grid(Bsz / 4);   // 4 waves/block, 1 seq/wave -> 512 blocks, 2048 waves
    dim3 block(256);
    hipLaunchKernelGGL(lstm2_pk1, grid, block, 0, stream,
                       x, Wih0, Whh0, bih0, bhh0,
                       Wih1, Whh1, bih1, bhh1, Wlin, blin, out);
}

// Round 7
// 895.254 us; speedup vs baseline: 1.0416x; 1.0416x over previous
//
#include <hip/hip_runtime.h>

// 2-layer LSTM, B=2048, T=4096, IN=1, H=8, OUT=1, fp32.
//
// R14 = R12 minus 3 dependency-chain steps. Model (R8/R11/R12/R13):
// wall = serial recurrence chain ~528cy/iter (22 dep steps x ~24cy);
// instruction count & DS latency are fully hidden by the 2 waves/SIMD.
// Cuts (all algebraically exact):
//  1. c-scale fold (R13-proven): g~ activation pre-scaled
//     (sA=2*N2L2E, oA=-N2L2E), state cs=c*N2L2E -> no mul before exp2.
//  2. recvB fold: t0 = fmaf(mL, recvB, fmaf(wx,xt,bias)) at body top
//     (off-chain); an1 accumulates from t0; z = an1 + s1 (add only).
//  3. h-fma merge: h = fmaf(go2, rcp, -go), go2=go+go off-critical.
//
// Layout: 1 seq/wave64, lane = L*32 + j*4 + g (g=gate i,f,g~,o; j=unit;
// L=layer). 2048 waves = 2 waves/SIMD.
// Near h (units j..j^3) via 5 intra-row DPPs. Far-half dot: each lane
// computes the far partial OF ITS MIRROR LANE's row (weights
// W[row(lane^16)][j^i]) from its near h; s1 ships via permlane16_swap
// (R11-verified), s2 via ds_swizzle xor16 (slack-covered). Cross-layer:
// d2 ships via ds_bpermute lane^32, consumed TWO iterations later:
// recvB(m) = d2(m-2) = Wih1 . h1(m-3)  =>  L1 runs THREE iters behind
// L0. Projection at iter m uses h2(m-4) -> store op[m-4]; fills = iters
// 0,1,2; steady m = 4..Tsz+3.
// Gates pre-scaled by -log2e (g~ rows -2log2e): act = rcp(1+exp2(z)).

constexpr int Bsz = 2048;
constexpr int Tsz = 4096;

typedef int v2i __attribute__((ext_vector_type(2)));

template <int CTRL>
__device__ __forceinline__ float dpp(float v) {
    return __int_as_float(
        __builtin_amdgcn_mov_dpp(__float_as_int(v), CTRL, 0xF, 0xF, true));
}
// quad_perm bcast0..3 = 0x00,0x55,0xAA,0xFF; quad xor3 = 0x1B;
// row_half_mirror (xor7) = 0x141; row_mirror (xor15) = 0x140

// v[lane^16] via V_PERMLANE16_SWAP_B32 (VALU; verified bit-exact in R11).
__device__ __forceinline__ float xchg16(float v, bool hi16) {
    const int vi = __float_as_int(v);
    v2i p = __builtin_amdgcn_permlane16_swap(vi, vi, false, false);
    return __int_as_float(hi16 ? p.x : p.y);
}

__device__ __forceinline__ float swz16(float v) {
    // ds_swizzle bit mode, xor 0x10 within each 32-lane group
    return __int_as_float(
        __builtin_amdgcn_ds_swizzle(__float_as_int(v), (16 << 10) | 0x1f));
}

__device__ __forceinline__ float bperm(int addr, float v) {
    return __int_as_float(__builtin_amdgcn_ds_bpermute(addr, __float_as_int(v)));
}

__global__ void __launch_bounds__(256, 2) lstm2_ch(
    const float* __restrict__ x,      // [B, T]
    const float* __restrict__ Wih0,   // [32, 1]
    const float* __restrict__ Whh0,   // [32, 8]
    const float* __restrict__ bih0,   // [32]
    const float* __restrict__ bhh0,   // [32]
    const float* __restrict__ Wih1,   // [32, 8]
    const float* __restrict__ Whh1,   // [32, 8]
    const float* __restrict__ bih1,   // [32]
    const float* __restrict__ bhh1,   // [32]
    const float* __restrict__ Wlin,   // [1, 8]
    const float* __restrict__ blin,   // [1]
    float* __restrict__ out)          // [B, T]
{
    const int tid  = threadIdx.x;
    const int lane = tid & 63;
    const int g    = lane & 3;
    const int j    = (lane >> 2) & 7;
    const int L    = (lane >> 5) & 1;
    const int seq  = blockIdx.x * 4 + (tid >> 6);

    const int jm = j ^ 4;             // mirror lane's unit
    const int r  = g * 8 + j;         // own gate row
    const int rm = g * 8 + jm;        // mirror lane's gate row

    const bool hi16 = (lane & 16) != 0;

    const float NL2E  = -1.4426950408889634f;
    const float N2L2E = -2.8853900817779268f;
    const bool  isG   = (g == 2);
    const float ws    = isG ? N2L2E : NL2E;
    // c-scale fold: g~ lanes produce tanh(g)*N2L2E directly
    const float sA    = isG ? 2.0f * N2L2E : 1.0f;
    const float oA    = isG ? -N2L2E : 0.0f;

    const float* __restrict__ Whh = L ? Whh1 : Whh0;
    const float* __restrict__ bih = L ? bih1 : bih0;
    const float* __restrict__ bhh = L ? bhh1 : bhh0;

    // near weights (own row) + mirror-row weights, k = j^i for i=0..3
    float wn1[4], wm1[4], wn2[4], wm2[4];
#pragma unroll
    for (int i = 0; i < 4; ++i) {
        const int k = j ^ i;
        wn1[i] = Whh[r * 8 + k] * ws;
        wm1[i] = Whh[rm * 8 + k] * ws;
        wn2[i] = L ? Wlin[k] : Wih1[r * 8 + k] * ws;
        wm2[i] = L ? Wlin[k] : Wih1[rm * 8 + k] * ws;
    }
    const float bias = (bih[r] + bhh[r]) * ws;
    const float wx   = L ? 0.0f : Wih0[r] * ws;
    const float b2   = L ? blin[0] : 0.0f;
    const float mL   = L ? 1.0f : 0.0f;
    const float keep = 1.0f - mL;
    const int  xaddr = (lane ^ 32) * 4;   // bpermute: cross layer halves

    const float* __restrict__ xp = x + (size_t)seq * Tsz;
    float* __restrict__ op       = out + (size_t)seq * Tsz;
    const bool storeLane = (lane == 32);

    float hn0 = 0.0f, hn1 = 0.0f, hn2 = 0.0f, hn3 = 0.0f;
    float cs = 0.0f;          // c' = c * N2L2E (scale-folded cell state)
    float recvA = 0.0f, recvB = 0.0f;

    auto body = [&](float xt, bool fill, float* storePtr) {
        // -- off-chain init: recvB folded into an1's base (cut #2)
        const float t0 = fmaf(mL, recvB, fmaf(wx, xt, bias));

        // -- mirror partials from entering hn (= h(m-1))
        float am2 = wm2[0] * hn0;
        am2 = fmaf(wm2[1], hn1, am2);
        am2 = fmaf(wm2[2], hn2, am2);
        am2 = fmaf(wm2[3], hn3, am2);
        const float s2 = swz16(am2);   // off-chain: ship via DS, consumed at tail

        float am1 = wm1[0] * hn0;
        am1 = fmaf(wm1[1], hn1, am1);
        am1 = fmaf(wm1[2], hn2, am1);
        am1 = fmaf(wm1[3], hn3, am1);
        const float s1 = xchg16(am1, hi16);   // ON-CHAIN: VALU permlane swap

        // -- near dots
        float an1 = fmaf(wn1[0], hn0, t0);
        an1 = fmaf(wn1[1], hn1, an1);
        an1 = fmaf(wn1[2], hn2, an1);
        an1 = fmaf(wn1[3], hn3, an1);
        float an2 = fmaf(wn2[0], hn0, b2);
        an2 = fmaf(wn2[1], hn1, an2);
        an2 = fmaf(wn2[2], hn2, an2);
        an2 = fmaf(wn2[3], hn3, an2);

        // -- z: near + far(ship); recvB already inside an1 (cut #2)
        const float z = an1 + s1;

        // -- activation (pre-scaled): sig, or tanh*N2L2E for g~ lanes
        float a = fmaf(sA,
                       __builtin_amdgcn_rcpf(1.0f + __builtin_amdgcn_exp2f(z)),
                       oA);
        const float gi = dpp<0x00>(a);
        const float gf = dpp<0x55>(a);
        const float gG = dpp<0xAA>(a);        // = tanh(g)*N2L2E (pre-scaled)
        const float go = dpp<0xFF>(a);
        const float go2 = go + go;            // off-critical (parallel w/ cs chain)
        cs = fmaf(gf, cs, gi * gG);           // c' = c*N2L2E (cut #1: no mul)
        const float e  = __builtin_amdgcn_exp2f(cs);
        const float rr = __builtin_amdgcn_rcpf(1.0f + e);
        float h = fmaf(go2, rr, -go);         // = go*(2*rr-1)  (cut #3)

        if (fill) { h *= keep; cs *= keep; }  // keep L1 state at zero

        // -- near-h gather for next iter (intra-row DPP only)
        const float m7  = dpp<0x141>(h);     // ^7
        const float m15 = dpp<0x140>(h);     // ^15
        hn0 = h;                             // j
        hn1 = dpp<0x1B>(m7);                 // ^7^3  = ^4  -> j^1
        hn2 = dpp<0x141>(m15);               // ^15^7 = ^8  -> j^2
        hn3 = dpp<0x1B>(m15);                // ^15^3 = ^12 -> j^3

        // -- tail: full spare dot (uses h(m-1) values), store, ship
        const float d2 = an2 + s2;           // L0: Wih1.h1(m-1); L1: proj(h2(m-4))
        if (storePtr && storeLane) *storePtr = d2;
        recvB = recvA;                       // recvB for iter m+1 = d2(m-1)
        recvA = bperm(xaddr, d2);            // d2(m), off-chain (2-iter slack)
    };

    // ---- fills: iters 0,1,2 keep L1 state zero; iter 3 = L1 step 0
    body(xp[0], true, nullptr);
    body(xp[1], true, nullptr);
    body(xp[2], true, nullptr);
    body(xp[3], false, nullptr);             // computes h2(0); proj invalid

    // ---- steady, unrolled x4: m = 4 .. Tsz+3, store op[m-4]
    float xc[4];
#pragma unroll
    for (int u = 0; u < 4; ++u) xc[u] = xp[4 + u];   // x(4..7), Tsz >> 8
    for (int ck = 0; ck < Tsz / 4; ++ck) {
        const int base = 4 + 4 * ck;
        float xf[4];
#pragma unroll
        for (int u = 0; u < 4; ++u) {
            int idx = base + 4 + u;
            idx = (idx < Tsz) ? idx : (Tsz - 1);
            xf[u] = xp[idx];                 // prefetch next chunk
        }
#pragma unroll
        for (int u = 0; u < 4; ++u)
            body(xc[u], false, op + (4 * ck + u));   // op[m-4]
#pragma unroll
        for (int u = 0; u < 4; ++u) xc[u] = xf[u];
    }
}

extern "C" void kernel_launch(void* const* d_in, const int* in_sizes, int n_in,
                              void* d_out, int out_size, void* d_ws, size_t ws_size,
                              hipStream_t stream) {
    const float* x    = (const float*)d_in[0];
    const float* Wih0 = (const float*)d_in[1];
    const float* Whh0 = (const float*)d_in[2];
    const float* bih0 = (const float*)d_in[3];
    const float* bhh0 = (const float*)d_in[4];
    const float* Wih1 = (const float*)d_in[5];
    const float* Whh1 = (const float*)d_in[6];
    const float* bih1 = (const float*)d_in[7];
    const float* bhh1 = (const float*)d_in[8];
    const float* Wlin = (const float*)d_in[9];
    const float* blin = (const float*)d_in[10];
    float* out = (float*)d_out;

    dim3 grid(Bsz / 4);   // 4 waves/block, 1 seq/wave -> 512 blocks, 2048 waves
    dim3 block(256);
    hipLaunchKernelGGL(lstm2_ch, grid, block, 0, stream,
                       x, Wih0, Whh0, bih0, bhh0,
                       Wih1, Whh1, bih1, bhh1, Wlin, blin, out);
}

// Round 8
// 855.401 us; speedup vs baseline: 1.0902x; 1.0466x over previous
//
#include <hip/hip_runtime.h>

// 2-layer LSTM, B=2048, T=4096, IN=1, H=8, OUT=1, fp32.
//
// R15 = R14 with the spare-dot DS ship DOUBLE-BUFFERED across bodies.
// Model refinement (R8..R14): wall 528cy/iter = issue ~430cy (2 waves)
// + ~100cy bubble. The bubble is the swz16(am2) lgkm wait: issued and
// consumed INSIDE one body (~60cy cover vs ~120cy DS latency). Fix:
// body(m) issues swz16; body(m+1) forms d2 = an2_hold + s2p at its TOP,
// stores it and ships via bperm (which already had full-body slack).
// Values are identical to R14, pipeline-shifted by one body:
//   d2_new(m) = d2_old(m-1); rB(m) = bperm(d2_old(m-2)) = recvB_old(m).
// => bit-identical output; store index op[m-5]; fills 0,1,2 zero L1;
// bodies 3,4 no store; steady m = 5..Tsz+4; L1 still 3 iters behind.
//
// Layout: 1 seq/wave64, lane = L*32 + j*4 + g (g=gate i,f,g~,o; j=unit;
// L=layer). 2048 waves = 2 waves/SIMD.
// Near h via 5 intra-row DPPs; far-half dots via mirror-row partials;
// s1 ships via permlane16_swap (on-chain, R11-verified); s2 via
// ds_swizzle xor16 (now full-body slack); cross-layer d2 via
// ds_bpermute lane^32 (full-body slack).
// Gates pre-scaled by -log2e (g~ rows -2log2e): act = rcp(1+exp2(z));
// c-scale fold cs = c*N2L2E (R13/R14-proven).

constexpr int Bsz = 2048;
constexpr int Tsz = 4096;

typedef int v2i __attribute__((ext_vector_type(2)));

template <int CTRL>
__device__ __forceinline__ float dpp(float v) {
    return __int_as_float(
        __builtin_amdgcn_mov_dpp(__float_as_int(v), CTRL, 0xF, 0xF, true));
}
// quad_perm bcast0..3 = 0x00,0x55,0xAA,0xFF; quad xor3 = 0x1B;
// row_half_mirror (xor7) = 0x141; row_mirror (xor15) = 0x140

// v[lane^16] via V_PERMLANE16_SWAP_B32 (VALU; verified bit-exact in R11).
__device__ __forceinline__ float xchg16(float v, bool hi16) {
    const int vi = __float_as_int(v);
    v2i p = __builtin_amdgcn_permlane16_swap(vi, vi, false, false);
    return __int_as_float(hi16 ? p.x : p.y);
}

__device__ __forceinline__ float swz16(float v) {
    // ds_swizzle bit mode, xor 0x10 within each 32-lane group
    return __int_as_float(
        __builtin_amdgcn_ds_swizzle(__float_as_int(v), (16 << 10) | 0x1f));
}

__device__ __forceinline__ float bperm(int addr, float v) {
    return __int_as_float(__builtin_amdgcn_ds_bpermute(addr, __float_as_int(v)));
}

__global__ void __launch_bounds__(256, 2) lstm2_dp(
    const float* __restrict__ x,      // [B, T]
    const float* __restrict__ Wih0,   // [32, 1]
    const float* __restrict__ Whh0,   // [32, 8]
    const float* __restrict__ bih0,   // [32]
    const float* __restrict__ bhh0,   // [32]
    const float* __restrict__ Wih1,   // [32, 8]
    const float* __restrict__ Whh1,   // [32, 8]
    const float* __restrict__ bih1,   // [32]
    const float* __restrict__ bhh1,   // [32]
    const float* __restrict__ Wlin,   // [1, 8]
    const float* __restrict__ blin,   // [1]
    float* __restrict__ out)          // [B, T]
{
    const int tid  = threadIdx.x;
    const int lane = tid & 63;
    const int g    = lane & 3;
    const int j    = (lane >> 2) & 7;
    const int L    = (lane >> 5) & 1;
    const int seq  = blockIdx.x * 4 + (tid >> 6);

    const int jm = j ^ 4;             // mirror lane's unit
    const int r  = g * 8 + j;         // own gate row
    const int rm = g * 8 + jm;        // mirror lane's gate row

    const bool hi16 = (lane & 16) != 0;

    const float NL2E  = -1.4426950408889634f;
    const float N2L2E = -2.8853900817779268f;
    const bool  isG   = (g == 2);
    const float ws    = isG ? N2L2E : NL2E;
    // c-scale fold: g~ lanes produce tanh(g)*N2L2E directly
    const float sA    = isG ? 2.0f * N2L2E : 1.0f;
    const float oA    = isG ? -N2L2E : 0.0f;

    const float* __restrict__ Whh = L ? Whh1 : Whh0;
    const float* __restrict__ bih = L ? bih1 : bih0;
    const float* __restrict__ bhh = L ? bhh1 : bhh0;

    // near weights (own row) + mirror-row weights, k = j^i for i=0..3
    float wn1[4], wm1[4], wn2[4], wm2[4];
#pragma unroll
    for (int i = 0; i < 4; ++i) {
        const int k = j ^ i;
        wn1[i] = Whh[r * 8 + k] * ws;
        wm1[i] = Whh[rm * 8 + k] * ws;
        wn2[i] = L ? Wlin[k] : Wih1[r * 8 + k] * ws;
        wm2[i] = L ? Wlin[k] : Wih1[rm * 8 + k] * ws;
    }
    const float bias = (bih[r] + bhh[r]) * ws;
    const float wx   = L ? 0.0f : Wih0[r] * ws;
    const float b2   = L ? blin[0] : 0.0f;
    const float mL   = L ? 1.0f : 0.0f;
    const float keep = 1.0f - mL;
    const int  xaddr = (lane ^ 32) * 4;   // bpermute: cross layer halves

    const float* __restrict__ xp = x + (size_t)seq * Tsz;
    float* __restrict__ op       = out + (size_t)seq * Tsz;
    const bool storeLane = (lane == 32);

    float hn0 = 0.0f, hn1 = 0.0f, hn2 = 0.0f, hn3 = 0.0f;
    float cs = 0.0f;          // c' = c * N2L2E (scale-folded cell state)
    float recvP = 0.0f;       // bperm result in flight (1-body slack)
    float an2_hold = 0.0f;    // near spare dot from previous body
    float s2p = 0.0f;         // swz16 result in flight (1-body slack)

    auto body = [&](float xt, bool fill, float* storePtr) {
        // ---- top: consume previous body's in-flight DS results
        const float d2 = an2_hold + s2p;   // = full spare dot of h(m-2)
        if (storePtr && storeLane) *storePtr = d2;   // proj(h2(m-7)) -> op[m-5]
        const float rB = recvP;            // bperm(d2(m-1)) result
        recvP = bperm(xaddr, d2);          // issue; consumed next body
        const float t0 = fmaf(mL, rB, fmaf(wx, xt, bias));

        // -- mirror partials from entering hn (= h(m-1))
        float am2 = wm2[0] * hn0;
        am2 = fmaf(wm2[1], hn1, am2);
        am2 = fmaf(wm2[2], hn2, am2);
        am2 = fmaf(wm2[3], hn3, am2);
        s2p = swz16(am2);                  // issue; consumed next body

        float am1 = wm1[0] * hn0;
        am1 = fmaf(wm1[1], hn1, am1);
        am1 = fmaf(wm1[2], hn2, am1);
        am1 = fmaf(wm1[3], hn3, am1);
        const float s1 = xchg16(am1, hi16);   // ON-CHAIN: VALU permlane swap

        // -- near dots
        float an1 = fmaf(wn1[0], hn0, t0);
        an1 = fmaf(wn1[1], hn1, an1);
        an1 = fmaf(wn1[2], hn2, an1);
        an1 = fmaf(wn1[3], hn3, an1);
        float an2 = fmaf(wn2[0], hn0, b2);
        an2 = fmaf(wn2[1], hn1, an2);
        an2 = fmaf(wn2[2], hn2, an2);
        an2 = fmaf(wn2[3], hn3, an2);
        an2_hold = an2;

        // -- z: near (incl. recvB via t0) + far(ship)
        const float z = an1 + s1;

        // -- activation (pre-scaled): sig, or tanh*N2L2E for g~ lanes
        float a = fmaf(sA,
                       __builtin_amdgcn_rcpf(1.0f + __builtin_amdgcn_exp2f(z)),
                       oA);
        const float gi = dpp<0x00>(a);
        const float gf = dpp<0x55>(a);
        const float gG = dpp<0xAA>(a);        // = tanh(g)*N2L2E (pre-scaled)
        const float go = dpp<0xFF>(a);
        const float go2 = go + go;            // off-critical
        cs = fmaf(gf, cs, gi * gG);           // c' = c*N2L2E
        const float e  = __builtin_amdgcn_exp2f(cs);
        const float rr = __builtin_amdgcn_rcpf(1.0f + e);
        float h = fmaf(go2, rr, -go);         // = go*(2*rr-1)

        if (fill) { h *= keep; cs *= keep; }  // keep L1 state at zero

        // -- near-h gather for next iter (intra-row DPP only)
        const float m7  = dpp<0x141>(h);     // ^7
        const float m15 = dpp<0x140>(h);     // ^15
        hn0 = h;                             // j
        hn1 = dpp<0x1B>(m7);                 // ^7^3  = ^4  -> j^1
        hn2 = dpp<0x141>(m15);               // ^15^7 = ^8  -> j^2
        hn3 = dpp<0x1B>(m15);                // ^15^3 = ^12 -> j^3
    };

    // ---- prologue: bodies 0,1,2 zero L1 state; 3,4 run free, no store
    body(xp[0], true, nullptr);
    body(xp[1], true, nullptr);
    body(xp[2], true, nullptr);
    body(xp[3], false, nullptr);
    body(xp[4], false, nullptr);

    // ---- steady, unrolled x4: m = 5 .. Tsz+4, store op[m-5]
    float xc[4];
#pragma unroll
    for (int u = 0; u < 4; ++u) xc[u] = xp[5 + u];   // x(5..8), Tsz >> 9
    for (int ck = 0; ck < Tsz / 4; ++ck) {
        const int base = 5 + 4 * ck;
        float xf[4];
#pragma unroll
        for (int u = 0; u < 4; ++u) {
            int idx = base + 4 + u;
            idx = (idx < Tsz) ? idx : (Tsz - 1);
            xf[u] = xp[idx];                 // prefetch next chunk (clamped)
        }
#pragma unroll
        for (int u = 0; u < 4; ++u)
            body(xc[u], false, op + (4 * ck + u));   // op[m-5]
#pragma unroll
        for (int u = 0; u < 4; ++u) xc[u] = xf[u];
    }
}

extern "C" void kernel_launch(void* const* d_in, const int* in_sizes, int n_in,
                              void* d_out, int out_size, void* d_ws, size_t ws_size,
                              hipStream_t stream) {
    const float* x    = (const float*)d_in[0];
    const float* Wih0 = (const float*)d_in[1];
    const float* Whh0 = (const float*)d_in[2];
    const float* bih0 = (const float*)d_in[3];
    const float* bhh0 = (const float*)d_in[4];
    const float* Wih1 = (const float*)d_in[5];
    const float* Whh1 = (const float*)d_in[6];
    const float* bih1 = (const float*)d_in[7];
    const float* bhh1 = (const float*)d_in[8];
    const float* Wlin = (const float*)d_in[9];
    const float* blin = (const float*)d_in[10];
    float* out = (float*)d_out;

    dim3 grid(Bsz / 4);   // 4 waves/block, 1 seq/wave -> 512 blocks, 2048 waves
    dim3 block(256);
    hipLaunchKernelGGL(lstm2_dp, grid, block, 0, stream,
                       x, Wih0, Whh0, bih0, bhh0,
                       Wih1, Whh1, bih1, bhh1, Wlin, blin, out);
}